// Round 5
// baseline (1566.589 us; speedup 1.0000x reference)
//
#include <hip/hip_runtime.h>
#include <hip/hip_bf16.h>
#include <cstddef>

#define BB 16
#define LL 2048
#define DM 128
#define DI 256
#define DS 16
#define MP (BB*LL)          // 32768 positions
#define NSEG 32
#define SEGLEN (LL/NSEG)    // 64

typedef __attribute__((ext_vector_type(8))) short bf16x8;
typedef __attribute__((ext_vector_type(4))) float f32x4;
typedef __hip_bfloat16 bf16;

__device__ inline void bf16split(float x, bf16& h, bf16& l) {
  h = __float2bfloat16(x);
  l = __float2bfloat16(x - __bfloat162float(h));
}
__device__ inline float bf2f(bf16 v) { return __bfloat162float(v); }

// ---------------------------------------------------------------------------
// Split-precision bf16 MFMA GEMM: C[M,N] = A[M,K] @ W[N,K]^T.
// Linear grid, N-tile FASTEST: bid%NT = n-tile, bid/NT = m-tile, so the NT
// consecutive (co-resident) blocks of one M-band write a complete contiguous
// 64-row x N fp32 band -> full 2KB DRAM rows, no strided-write collapse.
// ---------------------------------------------------------------------------
template<int ACCUM, int KT, int NT>
__global__ __launch_bounds__(256, 2) void gemm_mfma(
    const bf16* __restrict__ Ah, const bf16* __restrict__ Al,
    const bf16* __restrict__ Wh, const bf16* __restrict__ Wl,
    float* __restrict__ C, int ldc) {
  constexpr int NK = KT / 32;
  constexpr int CH = NK < 4 ? NK : 4;
  int bid = blockIdx.x;
  int tid = threadIdx.x;
  int wave = tid >> 6, lane = tid & 63;
  int r16 = lane & 15, quad = lane >> 4;
  int m0 = (bid / NT) * 64 + (wave & 1) * 32;
  int n0 = (bid % NT) * 64 + (wave >> 1) * 32;
  size_t arow[2], brow[2];
#pragma unroll
  for (int i = 0; i < 2; i++) {
    arow[i] = (size_t)(m0 + i * 16 + r16) * KT + quad * 8;
    brow[i] = (size_t)(n0 + i * 16 + r16) * KT + quad * 8;
  }
  f32x4 acc[2][2] = {};
#pragma unroll
  for (int c = 0; c < NK / CH; c++) {
    bf16x8 ah[2][CH], al[2][CH], bh[2][CH], bl[2][CH];
#pragma unroll
    for (int kk = 0; kk < CH; kk++) {
      int ko = (c * CH + kk) * 32;
#pragma unroll
      for (int i = 0; i < 2; i++) {
        ah[i][kk] = *(const bf16x8*)(Ah + arow[i] + ko);
        al[i][kk] = *(const bf16x8*)(Al + arow[i] + ko);
        bh[i][kk] = *(const bf16x8*)(Wh + brow[i] + ko);
        bl[i][kk] = *(const bf16x8*)(Wl + brow[i] + ko);
      }
    }
#pragma unroll
    for (int kk = 0; kk < CH; kk++)
#pragma unroll
      for (int i = 0; i < 2; i++)
#pragma unroll
        for (int j = 0; j < 2; j++) {
          acc[i][j] = __builtin_amdgcn_mfma_f32_16x16x32_bf16(ah[i][kk], bh[j][kk], acc[i][j], 0, 0, 0);
          acc[i][j] = __builtin_amdgcn_mfma_f32_16x16x32_bf16(ah[i][kk], bl[j][kk], acc[i][j], 0, 0, 0);
          acc[i][j] = __builtin_amdgcn_mfma_f32_16x16x32_bf16(al[i][kk], bh[j][kk], acc[i][j], 0, 0, 0);
        }
  }
#pragma unroll
  for (int i = 0; i < 2; i++)
#pragma unroll
    for (int j = 0; j < 2; j++)
#pragma unroll
      for (int r = 0; r < 4; r++) {
        int row = m0 + i * 16 + quad * 4 + r;
        int col = n0 + j * 16 + r16;
        if (ACCUM) C[(size_t)row * ldc + col] += acc[i][j][r];
        else       C[(size_t)row * ldc + col] = acc[i][j][r];
      }
}

// ---------------------------------------------------------------------------
// Fused out_proj + residual + RMSNorm. Block = 64 positions x full N=128.
// h += y @ Wop^T; then rmsnorm(h_row) with nw -> xn bf16 (next layer input);
// optional fp32 dump (final layer -> pooling input).
// ---------------------------------------------------------------------------
__global__ __launch_bounds__(256, 2) void outproj_norm(
    const bf16* __restrict__ Yh, const bf16* __restrict__ Yl,
    const bf16* __restrict__ Wh, const bf16* __restrict__ Wl,
    float* __restrict__ h, const float* __restrict__ nw,
    float* __restrict__ of, bf16* __restrict__ oh, bf16* __restrict__ ol) {
  __shared__ float tile[64 * 132];
  int bid = blockIdx.x;
  int tid = threadIdx.x;
  int wave = tid >> 6, lane = tid & 63;
  int r16 = lane & 15, quad = lane >> 4;
  int mh = wave & 1, nh = wave >> 1;
  int m0 = bid * 64 + mh * 32;
  int n0 = nh * 64;
  size_t arow[2], brow[4];
#pragma unroll
  for (int i = 0; i < 2; i++) arow[i] = (size_t)(m0 + i * 16 + r16) * DI + quad * 8;
#pragma unroll
  for (int j = 0; j < 4; j++) brow[j] = (size_t)(n0 + j * 16 + r16) * DI + quad * 8;
  f32x4 acc[2][4] = {};
#pragma unroll
  for (int c = 0; c < 4; c++) {
    bf16x8 ah[2][2], al[2][2], bh[4][2], bl[4][2];
#pragma unroll
    for (int kk = 0; kk < 2; kk++) {
      int ko = (c * 2 + kk) * 32;
#pragma unroll
      for (int i = 0; i < 2; i++) {
        ah[i][kk] = *(const bf16x8*)(Yh + arow[i] + ko);
        al[i][kk] = *(const bf16x8*)(Yl + arow[i] + ko);
      }
#pragma unroll
      for (int j = 0; j < 4; j++) {
        bh[j][kk] = *(const bf16x8*)(Wh + brow[j] + ko);
        bl[j][kk] = *(const bf16x8*)(Wl + brow[j] + ko);
      }
    }
#pragma unroll
    for (int kk = 0; kk < 2; kk++)
#pragma unroll
      for (int i = 0; i < 2; i++)
#pragma unroll
        for (int j = 0; j < 4; j++) {
          acc[i][j] = __builtin_amdgcn_mfma_f32_16x16x32_bf16(ah[i][kk], bh[j][kk], acc[i][j], 0, 0, 0);
          acc[i][j] = __builtin_amdgcn_mfma_f32_16x16x32_bf16(ah[i][kk], bl[j][kk], acc[i][j], 0, 0, 0);
          acc[i][j] = __builtin_amdgcn_mfma_f32_16x16x32_bf16(al[i][kk], bh[j][kk], acc[i][j], 0, 0, 0);
        }
  }
  // residual add into LDS tile (row-local = m within the 64-block)
#pragma unroll
  for (int i = 0; i < 2; i++)
#pragma unroll
    for (int j = 0; j < 4; j++)
#pragma unroll
      for (int r = 0; r < 4; r++) {
        int rl = mh * 32 + i * 16 + quad * 4 + r;
        int col = n0 + j * 16 + r16;
        size_t g = (size_t)(bid * 64 + rl) * DM + col;
        tile[rl * 132 + col] = acc[i][j][r] + h[g];
      }
  __syncthreads();
  // rmsnorm: 4 threads per row, 32 cols each
  int row = tid >> 2, part = tid & 3;
  const float* tr = tile + row * 132 + part * 32;
  float ss = 0.f;
#pragma unroll
  for (int c = 0; c < 32; c++) ss += tr[c] * tr[c];
  ss += __shfl_xor(ss, 1);
  ss += __shfl_xor(ss, 2);
  float sc = rsqrtf(ss * (1.f / DM) + 1e-5f);
  size_t gbase = (size_t)(bid * 64 + row) * DM + part * 32;
#pragma unroll
  for (int c = 0; c < 32; c++) {
    float v = tr[c];
    float nv = v * sc * nw[part * 32 + c];
    h[gbase + c] = v;
    if (of) of[gbase + c] = nv;
    bf16split(nv, oh[gbase + c], ol[gbase + c]);
  }
}

// ---------------------------------------------------------------------------
// Encoder: h[m,d] = sum_c x[m,c]*enc_w[d,c] + enc_b[d]   (K=12, direct)
// ---------------------------------------------------------------------------
__global__ __launch_bounds__(256) void encoder_kernel(const float* __restrict__ x,
    const float* __restrict__ ew, const float* __restrict__ eb,
    float* __restrict__ h) {
  int idx = blockIdx.x * 256 + threadIdx.x;   // m*128 + d
  int d = idx & 127, m = idx >> 7;
  float acc = eb[d];
#pragma unroll
  for (int c = 0; c < 12; c++) acc += x[m * 12 + c] * ew[d * 12 + c];
  h[idx] = acc;
}

// ---------------------------------------------------------------------------
// Weight split kernels (fp32 -> hi/lo bf16)
// ---------------------------------------------------------------------------
__global__ void split_w(const float* __restrict__ src, bf16* __restrict__ hi,
                        bf16* __restrict__ lo, int n) {
  int i = blockIdx.x * 256 + threadIdx.x;
  if (i < n) bf16split(src[i], hi[i], lo[i]);
}

__global__ void split_w_pad(const float* __restrict__ src, bf16* __restrict__ hi,
                            bf16* __restrict__ lo) {
  int i = blockIdx.x * 256 + threadIdx.x;   // < 4*64*256
  int l = i >> 14, rem = i & 16383, r = rem >> 8, k = rem & 255;
  float v = (r < 40) ? src[l * 10240 + r * 256 + k] : 0.f;
  bf16split(v, hi[i], lo[i]);
}

// ---------------------------------------------------------------------------
// RMSNorm (layer-0 input only)
// ---------------------------------------------------------------------------
__global__ __launch_bounds__(256) void rmsnorm_kernel(const float* __restrict__ x,
    const float* __restrict__ w, bf16* __restrict__ oh, bf16* __restrict__ ol) {
  int lane = threadIdx.x & 63;
  int pos = blockIdx.x * 4 + (threadIdx.x >> 6);
  const float* row = x + (size_t)pos * DM;
  float v0 = row[lane], v1 = row[lane + 64];
  float ss = v0 * v0 + v1 * v1;
#pragma unroll
  for (int off = 1; off < 64; off <<= 1) ss += __shfl_xor(ss, off);
  float sc = rsqrtf(ss * (1.f / DM) + 1e-5f);
  float a = v0 * sc * w[lane], b = v1 * sc * w[lane + 64];
  size_t o = (size_t)pos * DM;
  bf16split(a, oh[o + lane], ol[o + lane]);
  bf16split(b, oh[o + lane + 64], ol[o + lane + 64]);
}

// ---------------------------------------------------------------------------
// Causal depthwise conv (k=4) + bias + SiLU. Sliding-window registers.
// ---------------------------------------------------------------------------
__global__ __launch_bounds__(256) void conv_silu_kernel(const float* __restrict__ xz,
    const float* __restrict__ cw, const float* __restrict__ cb,
    bf16* __restrict__ oh, bf16* __restrict__ ol) {
  int d = threadIdx.x;
  int pos0 = blockIdx.x * 16;
  int l0 = pos0 & (LL - 1);
  float w0 = cw[d * 4], w1 = cw[d * 4 + 1], w2 = cw[d * 4 + 2], w3 = cw[d * 4 + 3];
  float bias = cb[d];
  float x0 = 0.f, x1 = 0.f, x2 = 0.f;
  if (l0 > 0) {
    x2 = xz[(size_t)(pos0 - 1) * 512 + d];
    x1 = xz[(size_t)(pos0 - 2) * 512 + d];
    x0 = xz[(size_t)(pos0 - 3) * 512 + d];
  }
#pragma unroll
  for (int t = 0; t < 16; t++) {
    int pos = pos0 + t;
    float x3 = xz[(size_t)pos * 512 + d];
    float acc = bias + w0 * x0 + w1 * x1 + w2 * x2 + w3 * x3;
    float s = acc / (1.f + __expf(-acc));
    bf16split(s, oh[(size_t)pos * 256 + d], ol[(size_t)pos * 256 + d]);
    x0 = x1; x1 = x2; x2 = x3;
  }
}

// ---------------------------------------------------------------------------
// Segmented selective scan (NSEG=32, SEGLEN=64). xdbl staged in LDS.
// FAST path exploits A[d][n] == -(n+1): dA[n] = exp(-dl)^(n+1).
// ---------------------------------------------------------------------------
__device__ inline float softplus_f(float a) {
  return fmaxf(a, 0.f) + log1pf(__expf(-fabsf(a)));
}

__device__ inline void make_powers(float r, float* rp) {
  rp[0] = r;
#pragma unroll
  for (int n = 1; n < 16; n++) {
    int a = (n + 1) >> 1, b = (n + 1) - a;
    rp[n] = rp[a - 1] * rp[b - 1];
  }
}

__device__ inline bool a_is_integer(const float* A_log, int d) {
  bool ok = true;
#pragma unroll
  for (int n = 0; n < DS; n++) {
    float Ad = -__expf(A_log[d * DS + n]);
    ok = ok && (fabsf(Ad + (float)(n + 1)) < 1e-3f);
  }
  return ok;
}

template<bool FAST>
__device__ inline void scan1_body(int s, int b, int d, const float* sx,
    const bf16* __restrict__ xc_hi, const bf16* __restrict__ xc_lo,
    const float* __restrict__ dtw, const float* __restrict__ dtb,
    const float* __restrict__ A_log,
    float* __restrict__ sega, float* __restrict__ segh) {
  float wdt[8];
#pragma unroll
  for (int j = 0; j < 8; j++) wdt[j] = dtw[d * 8 + j];
  float bdt = dtb[d];
  float h[DS];
#pragma unroll
  for (int n = 0; n < DS; n++) h[n] = 0.f;
  float R = 1.f;
  float ap[DS];
  if (!FAST) {
#pragma unroll
    for (int n = 0; n < DS; n++) ap[n] = 1.f;
  }
  size_t base = (size_t)b * LL + (size_t)s * SEGLEN;
#pragma unroll 4
  for (int t = 0; t < SEGLEN; t++) {
    size_t p = base + t;
    const float* xr = sx + t * 64;
    float dt = bdt;
#pragma unroll
    for (int j = 0; j < 8; j++) dt += xr[j] * wdt[j];
    float dl = softplus_f(dt);
    float u = bf2f(xc_hi[p * 256 + d]) + bf2f(xc_lo[p * 256 + d]);
    float du = dl * u;
    if (FAST) {
      float rp[DS];
      make_powers(__expf(-dl), rp);
      R *= rp[0];
#pragma unroll
      for (int n = 0; n < DS; n++) h[n] = fmaf(rp[n], h[n], du * xr[8 + n]);
    } else {
#pragma unroll
      for (int n = 0; n < DS; n++) {
        float dA = __expf(dl * (-__expf(A_log[d * DS + n])));
        h[n] = fmaf(dA, h[n], du * xr[8 + n]);
        ap[n] *= dA;
      }
    }
  }
  if (FAST) make_powers(R, ap);
  size_t o = ((size_t)s * 4096 + b * 256 + d) * DS;
#pragma unroll
  for (int j = 0; j < 4; j++) {
    *(float4*)(sega + o + 4 * j) = make_float4(ap[4*j], ap[4*j+1], ap[4*j+2], ap[4*j+3]);
    *(float4*)(segh + o + 4 * j) = make_float4(h[4*j], h[4*j+1], h[4*j+2], h[4*j+3]);
  }
}

__global__ __launch_bounds__(256, 2) void scan_phase1(
    const bf16* __restrict__ xc_hi, const bf16* __restrict__ xc_lo,
    const float* __restrict__ xdbl, const float* __restrict__ dtw,
    const float* __restrict__ dtb, const float* __restrict__ A_log,
    float* __restrict__ sega, float* __restrict__ segh) {
  __shared__ float sx[SEGLEN * 64];
  int s = blockIdx.x, b = blockIdx.y, d = threadIdx.x;
  size_t rbase = ((size_t)b * LL + (size_t)s * SEGLEN) * 64;
#pragma unroll
  for (int j = 0; j < 4; j++)
    *(float4*)(sx + j * 1024 + d * 4) = *(const float4*)(xdbl + rbase + j * 1024 + d * 4);
  __syncthreads();
  if (a_is_integer(A_log, d))
    scan1_body<true>(s, b, d, sx, xc_hi, xc_lo, dtw, dtb, A_log, sega, segh);
  else
    scan1_body<false>(s, b, d, sx, xc_hi, xc_lo, dtw, dtb, A_log, sega, segh);
}

__global__ __launch_bounds__(256) void scan_combine(float* __restrict__ sega,
    const float* __restrict__ segh) {
  int g = blockIdx.x * 256 + threadIdx.x;   // 16384 groups of 4 states
  size_t off = (size_t)(g >> 2) * 16 + (g & 3) * 4;
  float4 h0 = make_float4(0.f, 0.f, 0.f, 0.f);
  for (int s = 0; s < NSEG; s++) {
    size_t q = (size_t)s * 65536 + off;
    float4 a = *(float4*)(sega + q);
    float4 hh = *(float4*)(segh + q);
    *(float4*)(sega + q) = h0;
    h0.x = a.x * h0.x + hh.x;
    h0.y = a.y * h0.y + hh.y;
    h0.z = a.z * h0.z + hh.z;
    h0.w = a.w * h0.w + hh.w;
  }
}

template<bool FAST>
__device__ inline void scan2_body(int s, int b, int d, const float* sx,
    const bf16* __restrict__ xc_hi, const bf16* __restrict__ xc_lo,
    const float* __restrict__ xz, const float* __restrict__ dtw,
    const float* __restrict__ dtb, const float* __restrict__ A_log,
    const float* __restrict__ Dp, const float* __restrict__ sega,
    bf16* __restrict__ y_hi, bf16* __restrict__ y_lo) {
  float wdt[8];
#pragma unroll
  for (int j = 0; j < 8; j++) wdt[j] = dtw[d * 8 + j];
  float bdt = dtb[d];
  float h[DS];
  size_t o = ((size_t)s * 4096 + b * 256 + d) * DS;
#pragma unroll
  for (int n = 0; n < DS; n++) h[n] = sega[o + n];
  float Dd = Dp[d];
  size_t base = (size_t)b * LL + (size_t)s * SEGLEN;
#pragma unroll 4
  for (int t = 0; t < SEGLEN; t++) {
    size_t p = base + t;
    const float* xr = sx + t * 64;
    float dt = bdt;
#pragma unroll
    for (int j = 0; j < 8; j++) dt += xr[j] * wdt[j];
    float dl = softplus_f(dt);
    float u = bf2f(xc_hi[p * 256 + d]) + bf2f(xc_lo[p * 256 + d]);
    float du = dl * u;
    float acc = 0.f;
    if (FAST) {
      float rp[DS];
      make_powers(__expf(-dl), rp);
#pragma unroll
      for (int n = 0; n < DS; n++) {
        h[n] = fmaf(rp[n], h[n], du * xr[8 + n]);
        acc = fmaf(h[n], xr[24 + n], acc);
      }
    } else {
#pragma unroll
      for (int n = 0; n < DS; n++) {
        float dA = __expf(dl * (-__expf(A_log[d * DS + n])));
        h[n] = fmaf(dA, h[n], du * xr[8 + n]);
        acc = fmaf(h[n], xr[24 + n], acc);
      }
    }
    float zv = xz[p * 512 + 256 + d];
    float sig = 1.f / (1.f + __expf(-zv));
    float yv = (acc + u * Dd) * (zv * sig);
    bf16split(yv, y_hi[p * 256 + d], y_lo[p * 256 + d]);
  }
}

__global__ __launch_bounds__(256, 2) void scan_phase2(
    const bf16* __restrict__ xc_hi, const bf16* __restrict__ xc_lo,
    const float* __restrict__ xdbl, const float* __restrict__ xz,
    const float* __restrict__ dtw, const float* __restrict__ dtb,
    const float* __restrict__ A_log, const float* __restrict__ Dp,
    const float* __restrict__ sega, bf16* __restrict__ y_hi,
    bf16* __restrict__ y_lo) {
  __shared__ float sx[SEGLEN * 64];
  int s = blockIdx.x, b = blockIdx.y, d = threadIdx.x;
  size_t rbase = ((size_t)b * LL + (size_t)s * SEGLEN) * 64;
#pragma unroll
  for (int j = 0; j < 4; j++)
    *(float4*)(sx + j * 1024 + d * 4) = *(const float4*)(xdbl + rbase + j * 1024 + d * 4);
  __syncthreads();
  if (a_is_integer(A_log, d))
    scan2_body<true>(s, b, d, sx, xc_hi, xc_lo, xz, dtw, dtb, A_log, Dp, sega, y_hi, y_lo);
  else
    scan2_body<false>(s, b, d, sx, xc_hi, xc_lo, xz, dtw, dtb, A_log, Dp, sega, y_hi, y_lo);
}

// ---------------------------------------------------------------------------
// Final pooling + classifier
// ---------------------------------------------------------------------------
__global__ void zero_kernel(float* __restrict__ p, int n) {
  int i = blockIdx.x * 256 + threadIdx.x;
  if (i < n) p[i] = 0.f;
}

__global__ __launch_bounds__(256) void pool_kernel(const float* __restrict__ xn,
    float* __restrict__ pooled) {
  int b = blockIdx.x, chunk = blockIdx.y;
  int d = threadIdx.x & 127, lh = threadIdx.x >> 7;
  float s = 0.f;
  size_t base = (size_t)b * LL + chunk * 256 + lh * 128;
  for (int i = 0; i < 128; i++) s += xn[(base + i) * DM + d];
  atomicAdd(&pooled[b * DM + d], s * (1.f / LL));
}

__global__ void cls_kernel(const float* __restrict__ pooled,
    const float* __restrict__ cw, const float* __restrict__ cb,
    float* __restrict__ out) {
  int t = threadIdx.x;
  if (t < 80) {
    int b = t / 5, c = t % 5;
    float acc = cb[c];
    for (int d = 0; d < DM; d++) acc += pooled[b * DM + d] * cw[c * DM + d];
    out[t] = acc;
  }
}

// ---------------------------------------------------------------------------
extern "C" void kernel_launch(void* const* d_in, const int* in_sizes, int n_in,
                              void* d_out, int out_size, void* d_ws, size_t ws_size,
                              hipStream_t stream) {
  const float* x         = (const float*)d_in[0];
  const float* enc_w     = (const float*)d_in[1];
  const float* enc_b     = (const float*)d_in[2];
  const float* norm_w    = (const float*)d_in[3];
  const float* in_proj_w = (const float*)d_in[4];
  const float* conv_w    = (const float*)d_in[5];
  const float* conv_b    = (const float*)d_in[6];
  const float* x_proj_w  = (const float*)d_in[7];
  const float* dt_proj_w = (const float*)d_in[8];
  const float* dt_proj_b = (const float*)d_in[9];
  const float* A_log     = (const float*)d_in[10];
  const float* Dp        = (const float*)d_in[11];
  const float* out_proj_w= (const float*)d_in[12];
  const float* norm_f_w  = (const float*)d_in[13];
  const float* cls_w     = (const float*)d_in[14];
  const float* cls_b     = (const float*)d_in[15];
  float* out = (float*)d_out;

  float* ws = (float*)d_ws;
  float* h      = ws;                  // 4,194,304
  float* xz     = ws + 4194304;        // 16,777,216 (reused as fnorm scratch)
  float* xdbl   = ws + 20971520;       // 2,097,152
  float* sega   = ws + 23068672;       // 2,097,152 (NSEG=32)
  float* segh   = ws + 25165824;       // 2,097,152
  float* pooled = ws + 27262976;       // 2048
  bf16* u0     = (bf16*)(ws + 27265024);
  bf16* xn_hi  = u0;                   // 4,194,304
  bf16* xn_lo  = u0 + 4194304;
  bf16* xc_hi  = u0 + 8388608;         // 8,388,608
  bf16* xc_lo  = u0 + 16777216;
  bf16* y_hi   = u0 + 25165824;        // 8,388,608
  bf16* y_lo   = u0 + 33554432;
  bf16* wip_hi = u0 + 41943040;        // 262,144
  bf16* wip_lo = wip_hi + 262144;
  bf16* wxp_hi = wip_lo + 262144;      // 65,536 (padded)
  bf16* wxp_lo = wxp_hi + 65536;
  bf16* wop_hi = wxp_lo + 65536;       // 131,072
  bf16* wop_lo = wop_hi + 131072;
  float* fnorm = xz;                   // xz dead after last scan_phase2

  split_w<<<1024, 256, 0, stream>>>(in_proj_w, wip_hi, wip_lo, 262144);
  split_w_pad<<<256, 256, 0, stream>>>(x_proj_w, wxp_hi, wxp_lo);
  split_w<<<512, 256, 0, stream>>>(out_proj_w, wop_hi, wop_lo, 131072);

  encoder_kernel<<<MP * DM / 256, 256, 0, stream>>>(x, enc_w, enc_b, h);
  rmsnorm_kernel<<<MP / 4, 256, 0, stream>>>(h, norm_w, xn_hi, xn_lo);

  for (int i = 0; i < 4; i++) {
    gemm_mfma<0, 128, 8><<<4096, 256, 0, stream>>>(xn_hi, xn_lo,
        wip_hi + i * 65536, wip_lo + i * 65536, xz, 512);
    conv_silu_kernel<<<MP / 16, 256, 0, stream>>>(xz, conv_w + i * DI * 4,
        conv_b + i * DI, xc_hi, xc_lo);
    gemm_mfma<0, 256, 1><<<512, 256, 0, stream>>>(xc_hi, xc_lo,
        wxp_hi + i * 16384, wxp_lo + i * 16384, xdbl, 64);
    scan_phase1<<<dim3(NSEG, BB), 256, 0, stream>>>(xc_hi, xc_lo, xdbl,
        dt_proj_w + i * 2048, dt_proj_b + i * DI, A_log + i * DI * DS, sega, segh);
    scan_combine<<<64, 256, 0, stream>>>(sega, segh);
    scan_phase2<<<dim3(NSEG, BB), 256, 0, stream>>>(xc_hi, xc_lo, xdbl, xz,
        dt_proj_w + i * 2048, dt_proj_b + i * DI, A_log + i * DI * DS,
        Dp + i * DI, sega, y_hi, y_lo);
    // fused: h += y @ Wop^T; rmsnorm(next norm weight) -> xn (+ fp32 for pooling at i=3)
    outproj_norm<<<512, 256, 0, stream>>>(y_hi, y_lo,
        wop_hi + i * 32768, wop_lo + i * 32768, h,
        (i < 3) ? norm_w + (i + 1) * DM : norm_f_w,
        (i < 3) ? nullptr : fnorm, xn_hi, xn_lo);
  }

  zero_kernel<<<8, 256, 0, stream>>>(pooled, BB * DM);
  pool_kernel<<<dim3(BB, 8), 256, 0, stream>>>(fnorm, pooled);
  cls_kernel<<<1, 128, 0, stream>>>(pooled, cls_w, cls_b, out);
}

// Round 7
// 1044.119 us; speedup vs baseline: 1.5004x; 1.5004x over previous
//
#include <hip/hip_runtime.h>
#include <hip/hip_bf16.h>
#include <cstddef>

#define BB 16
#define LL 2048
#define DM 128
#define DI 256
#define DS 16
#define MP (BB*LL)          // 32768 positions
#define NSEG 32
#define SEGLEN (LL/NSEG)    // 64

typedef __attribute__((ext_vector_type(8))) short bf16x8;
typedef __attribute__((ext_vector_type(4))) short bf16x4s;
typedef __attribute__((ext_vector_type(4))) float f32x4;
typedef __hip_bfloat16 bf16;

__device__ inline void bf16split(float x, bf16& h, bf16& l) {
  h = __float2bfloat16(x);
  l = __float2bfloat16(x - __bfloat162float(h));
}
__device__ inline float bf2f(bf16 v) { return __bfloat162float(v); }
// split into raw short bits (for packed vector stores)
__device__ inline void split_bits(float x, short& hs, short& ls) {
  bf16 hb = __float2bfloat16(x);
  bf16 lb = __float2bfloat16(x - __bfloat162float(hb));
  hs = *(short*)&hb;
  ls = *(short*)&lb;
}

// ---------------------------------------------------------------------------
// Split-precision bf16 MFMA GEMM: C[M,N] = A[M,K] @ W[N,K]^T.
// Linear grid, N-tile fastest (contiguous row-band writes per block group).
// ---------------------------------------------------------------------------
template<int ACCUM, int KT, int NT>
__global__ __launch_bounds__(256, 2) void gemm_mfma(
    const bf16* __restrict__ Ah, const bf16* __restrict__ Al,
    const bf16* __restrict__ Wh, const bf16* __restrict__ Wl,
    float* __restrict__ C, int ldc) {
  constexpr int NK = KT / 32;
  constexpr int CH = NK < 4 ? NK : 4;
  int bid = blockIdx.x;
  int tid = threadIdx.x;
  int wave = tid >> 6, lane = tid & 63;
  int r16 = lane & 15, quad = lane >> 4;
  int m0 = (bid / NT) * 64 + (wave & 1) * 32;
  int n0 = (bid % NT) * 64 + (wave >> 1) * 32;
  size_t arow[2], brow[2];
#pragma unroll
  for (int i = 0; i < 2; i++) {
    arow[i] = (size_t)(m0 + i * 16 + r16) * KT + quad * 8;
    brow[i] = (size_t)(n0 + i * 16 + r16) * KT + quad * 8;
  }
  f32x4 acc[2][2] = {};
#pragma unroll
  for (int c = 0; c < NK / CH; c++) {
    bf16x8 ah[2][CH], al[2][CH], bh[2][CH], bl[2][CH];
#pragma unroll
    for (int kk = 0; kk < CH; kk++) {
      int ko = (c * CH + kk) * 32;
#pragma unroll
      for (int i = 0; i < 2; i++) {
        ah[i][kk] = *(const bf16x8*)(Ah + arow[i] + ko);
        al[i][kk] = *(const bf16x8*)(Al + arow[i] + ko);
        bh[i][kk] = *(const bf16x8*)(Wh + brow[i] + ko);
        bl[i][kk] = *(const bf16x8*)(Wl + brow[i] + ko);
      }
    }
#pragma unroll
    for (int kk = 0; kk < CH; kk++)
#pragma unroll
      for (int i = 0; i < 2; i++)
#pragma unroll
        for (int j = 0; j < 2; j++) {
          acc[i][j] = __builtin_amdgcn_mfma_f32_16x16x32_bf16(ah[i][kk], bh[j][kk], acc[i][j], 0, 0, 0);
          acc[i][j] = __builtin_amdgcn_mfma_f32_16x16x32_bf16(ah[i][kk], bl[j][kk], acc[i][j], 0, 0, 0);
          acc[i][j] = __builtin_amdgcn_mfma_f32_16x16x32_bf16(al[i][kk], bh[j][kk], acc[i][j], 0, 0, 0);
        }
  }
#pragma unroll
  for (int i = 0; i < 2; i++)
#pragma unroll
    for (int j = 0; j < 2; j++)
#pragma unroll
      for (int r = 0; r < 4; r++) {
        int row = m0 + i * 16 + quad * 4 + r;
        int col = n0 + j * 16 + r16;
        if (ACCUM) C[(size_t)row * ldc + col] += acc[i][j][r];
        else       C[(size_t)row * ldc + col] = acc[i][j][r];
      }
}

// ---------------------------------------------------------------------------
// Fused out_proj + residual + RMSNorm. Block = 64 positions x full N=128.
// MFMA acc -> LDS tile; epilogue fully wave-coalesced (float4 / 8B stores).
// ---------------------------------------------------------------------------
__global__ __launch_bounds__(256, 2) void outproj_norm(
    const bf16* __restrict__ Yh, const bf16* __restrict__ Yl,
    const bf16* __restrict__ Wh, const bf16* __restrict__ Wl,
    float* __restrict__ h, const float* __restrict__ nw,
    float* __restrict__ of, bf16* __restrict__ oh, bf16* __restrict__ ol) {
  __shared__ float tile[64 * 132];
  int bid = blockIdx.x;
  int tid = threadIdx.x;
  int wave = tid >> 6, lane = tid & 63;
  int r16 = lane & 15, quad = lane >> 4;
  int mh = wave & 1, nh = wave >> 1;
  int m0 = bid * 64 + mh * 32;
  int n0 = nh * 64;
  size_t arow[2], brow[4];
#pragma unroll
  for (int i = 0; i < 2; i++) arow[i] = (size_t)(m0 + i * 16 + r16) * DI + quad * 8;
#pragma unroll
  for (int j = 0; j < 4; j++) brow[j] = (size_t)(n0 + j * 16 + r16) * DI + quad * 8;
  f32x4 acc[2][4] = {};
#pragma unroll
  for (int c = 0; c < 4; c++) {
    bf16x8 ah[2][2], al[2][2], bh[4][2], bl[4][2];
#pragma unroll
    for (int kk = 0; kk < 2; kk++) {
      int ko = (c * 2 + kk) * 32;
#pragma unroll
      for (int i = 0; i < 2; i++) {
        ah[i][kk] = *(const bf16x8*)(Yh + arow[i] + ko);
        al[i][kk] = *(const bf16x8*)(Yl + arow[i] + ko);
      }
#pragma unroll
      for (int j = 0; j < 4; j++) {
        bh[j][kk] = *(const bf16x8*)(Wh + brow[j] + ko);
        bl[j][kk] = *(const bf16x8*)(Wl + brow[j] + ko);
      }
    }
#pragma unroll
    for (int kk = 0; kk < 2; kk++)
#pragma unroll
      for (int i = 0; i < 2; i++)
#pragma unroll
        for (int j = 0; j < 4; j++) {
          acc[i][j] = __builtin_amdgcn_mfma_f32_16x16x32_bf16(ah[i][kk], bh[j][kk], acc[i][j], 0, 0, 0);
          acc[i][j] = __builtin_amdgcn_mfma_f32_16x16x32_bf16(ah[i][kk], bl[j][kk], acc[i][j], 0, 0, 0);
          acc[i][j] = __builtin_amdgcn_mfma_f32_16x16x32_bf16(al[i][kk], bh[j][kk], acc[i][j], 0, 0, 0);
        }
  }
  // acc -> LDS tile
#pragma unroll
  for (int i = 0; i < 2; i++)
#pragma unroll
    for (int j = 0; j < 4; j++)
#pragma unroll
      for (int r = 0; r < 4; r++) {
        int rl = mh * 32 + i * 16 + quad * 4 + r;
        int col = n0 + j * 16 + r16;
        tile[rl * 132 + col] = acc[i][j][r];
      }
  __syncthreads();
  // coalesced epilogue: residual + rmsnorm + bf16 split
#pragma unroll
  for (int it = 0; it < 8; it++) {
    int idx = it * 256 + tid;
    int row = idx >> 5, c4 = idx & 31;
    size_t g = (size_t)(bid * 64 + row) * DM + c4 * 4;
    float4 hv = *(float4*)(h + g);
    const float* tp = tile + row * 132 + c4 * 4;
    float4 v = make_float4(tp[0] + hv.x, tp[1] + hv.y, tp[2] + hv.z, tp[3] + hv.w);
    *(float4*)(h + g) = v;
    float ss = v.x * v.x + v.y * v.y + v.z * v.z + v.w * v.w;
    ss += __shfl_xor(ss, 1);
    ss += __shfl_xor(ss, 2);
    ss += __shfl_xor(ss, 4);
    ss += __shfl_xor(ss, 8);
    ss += __shfl_xor(ss, 16);
    float sc = rsqrtf(ss * (1.f / DM) + 1e-5f);
    float4 w4 = *(const float4*)(nw + c4 * 4);
    float n0v = v.x * sc * w4.x, n1v = v.y * sc * w4.y;
    float n2v = v.z * sc * w4.z, n3v = v.w * sc * w4.w;
    if (of) *(float4*)(of + g) = make_float4(n0v, n1v, n2v, n3v);
    short h0s, l0s, h1s, l1s, h2s, l2s, h3s, l3s;
    split_bits(n0v, h0s, l0s);
    split_bits(n1v, h1s, l1s);
    split_bits(n2v, h2s, l2s);
    split_bits(n3v, h3s, l3s);
    bf16x4s hb, lb;
    hb.x = h0s; hb.y = h1s; hb.z = h2s; hb.w = h3s;
    lb.x = l0s; lb.y = l1s; lb.z = l2s; lb.w = l3s;
    *(bf16x4s*)(oh + g) = hb;
    *(bf16x4s*)(ol + g) = lb;
  }
}

// ---------------------------------------------------------------------------
// Encoder: h[m,d] = sum_c x[m,c]*enc_w[d,c] + enc_b[d]   (K=12, direct)
// ---------------------------------------------------------------------------
__global__ __launch_bounds__(256) void encoder_kernel(const float* __restrict__ x,
    const float* __restrict__ ew, const float* __restrict__ eb,
    float* __restrict__ h) {
  int idx = blockIdx.x * 256 + threadIdx.x;   // m*128 + d
  int d = idx & 127, m = idx >> 7;
  float acc = eb[d];
#pragma unroll
  for (int c = 0; c < 12; c++) acc += x[m * 12 + c] * ew[d * 12 + c];
  h[idx] = acc;
}

// ---------------------------------------------------------------------------
// Weight split kernels (fp32 -> hi/lo bf16)
// ---------------------------------------------------------------------------
__global__ void split_w(const float* __restrict__ src, bf16* __restrict__ hi,
                        bf16* __restrict__ lo, int n) {
  int i = blockIdx.x * 256 + threadIdx.x;
  if (i < n) bf16split(src[i], hi[i], lo[i]);
}

__global__ void split_w_pad(const float* __restrict__ src, bf16* __restrict__ hi,
                            bf16* __restrict__ lo) {
  int i = blockIdx.x * 256 + threadIdx.x;   // < 4*64*256
  int l = i >> 14, rem = i & 16383, r = rem >> 8, k = rem & 255;
  float v = (r < 40) ? src[l * 10240 + r * 256 + k] : 0.f;
  bf16split(v, hi[i], lo[i]);
}

// ---------------------------------------------------------------------------
// RMSNorm (layer-0 input only)
// ---------------------------------------------------------------------------
__global__ __launch_bounds__(256) void rmsnorm_kernel(const float* __restrict__ x,
    const float* __restrict__ w, bf16* __restrict__ oh, bf16* __restrict__ ol) {
  int lane = threadIdx.x & 63;
  int pos = blockIdx.x * 4 + (threadIdx.x >> 6);
  const float* row = x + (size_t)pos * DM;
  float v0 = row[lane], v1 = row[lane + 64];
  float ss = v0 * v0 + v1 * v1;
#pragma unroll
  for (int off = 1; off < 64; off <<= 1) ss += __shfl_xor(ss, off);
  float sc = rsqrtf(ss * (1.f / DM) + 1e-5f);
  float a = v0 * sc * w[lane], b = v1 * sc * w[lane + 64];
  size_t o = (size_t)pos * DM;
  bf16split(a, oh[o + lane], ol[o + lane]);
  bf16split(b, oh[o + lane + 64], ol[o + lane + 64]);
}

// ---------------------------------------------------------------------------
// Causal depthwise conv (k=4) + bias + SiLU. Sliding-window registers.
// ---------------------------------------------------------------------------
__global__ __launch_bounds__(256) void conv_silu_kernel(const float* __restrict__ xz,
    const float* __restrict__ cw, const float* __restrict__ cb,
    bf16* __restrict__ oh, bf16* __restrict__ ol) {
  int d = threadIdx.x;
  int pos0 = blockIdx.x * 16;
  int l0 = pos0 & (LL - 1);
  float w0 = cw[d * 4], w1 = cw[d * 4 + 1], w2 = cw[d * 4 + 2], w3 = cw[d * 4 + 3];
  float bias = cb[d];
  float x0 = 0.f, x1 = 0.f, x2 = 0.f;
  if (l0 > 0) {
    x2 = xz[(size_t)(pos0 - 1) * 512 + d];
    x1 = xz[(size_t)(pos0 - 2) * 512 + d];
    x0 = xz[(size_t)(pos0 - 3) * 512 + d];
  }
#pragma unroll
  for (int t = 0; t < 16; t++) {
    int pos = pos0 + t;
    float x3 = xz[(size_t)pos * 512 + d];
    float acc = bias + w0 * x0 + w1 * x1 + w2 * x2 + w3 * x3;
    float s = acc / (1.f + __expf(-acc));
    bf16split(s, oh[(size_t)pos * 256 + d], ol[(size_t)pos * 256 + d]);
    x0 = x1; x1 = x2; x2 = x3;
  }
}

// ---------------------------------------------------------------------------
// Segmented selective scan (NSEG=32, SEGLEN=64). xdbl staged in LDS.
// FAST path exploits A[d][n] == -(n+1): dA[n] = exp(-dl)^(n+1).
// ---------------------------------------------------------------------------
__device__ inline float softplus_f(float a) {
  return fmaxf(a, 0.f) + log1pf(__expf(-fabsf(a)));
}

__device__ inline void make_powers(float r, float* rp) {
  rp[0] = r;
#pragma unroll
  for (int n = 1; n < 16; n++) {
    int a = (n + 1) >> 1, b = (n + 1) - a;
    rp[n] = rp[a - 1] * rp[b - 1];
  }
}

__device__ inline bool a_is_integer(const float* A_log, int d) {
  bool ok = true;
#pragma unroll
  for (int n = 0; n < DS; n++) {
    float Ad = -__expf(A_log[d * DS + n]);
    ok = ok && (fabsf(Ad + (float)(n + 1)) < 1e-3f);
  }
  return ok;
}

template<bool FAST>
__device__ inline void scan1_body(int s, int b, int d, const float* sx,
    const bf16* __restrict__ xc_hi, const bf16* __restrict__ xc_lo,
    const float* __restrict__ dtw, const float* __restrict__ dtb,
    const float* __restrict__ A_log,
    float* __restrict__ sega, float* __restrict__ segh) {
  float wdt[8];
#pragma unroll
  for (int j = 0; j < 8; j++) wdt[j] = dtw[d * 8 + j];
  float bdt = dtb[d];
  float h[DS];
#pragma unroll
  for (int n = 0; n < DS; n++) h[n] = 0.f;
  float R = 1.f;
  float ap[DS];
  if (!FAST) {
#pragma unroll
    for (int n = 0; n < DS; n++) ap[n] = 1.f;
  }
  size_t base = (size_t)b * LL + (size_t)s * SEGLEN;
#pragma unroll 4
  for (int t = 0; t < SEGLEN; t++) {
    size_t p = base + t;
    const float* xr = sx + t * 64;
    float dt = bdt;
#pragma unroll
    for (int j = 0; j < 8; j++) dt += xr[j] * wdt[j];
    float dl = softplus_f(dt);
    float u = bf2f(xc_hi[p * 256 + d]) + bf2f(xc_lo[p * 256 + d]);
    float du = dl * u;
    if (FAST) {
      float rp[DS];
      make_powers(__expf(-dl), rp);
      R *= rp[0];
#pragma unroll
      for (int n = 0; n < DS; n++) h[n] = fmaf(rp[n], h[n], du * xr[8 + n]);
    } else {
#pragma unroll
      for (int n = 0; n < DS; n++) {
        float dA = __expf(dl * (-__expf(A_log[d * DS + n])));
        h[n] = fmaf(dA, h[n], du * xr[8 + n]);
        ap[n] *= dA;
      }
    }
  }
  if (FAST) make_powers(R, ap);
  size_t o = ((size_t)s * 4096 + b * 256 + d) * DS;
#pragma unroll
  for (int j = 0; j < 4; j++) {
    *(float4*)(sega + o + 4 * j) = make_float4(ap[4*j], ap[4*j+1], ap[4*j+2], ap[4*j+3]);
    *(float4*)(segh + o + 4 * j) = make_float4(h[4*j], h[4*j+1], h[4*j+2], h[4*j+3]);
  }
}

__global__ __launch_bounds__(256, 2) void scan_phase1(
    const bf16* __restrict__ xc_hi, const bf16* __restrict__ xc_lo,
    const float* __restrict__ xdbl, const float* __restrict__ dtw,
    const float* __restrict__ dtb, const float* __restrict__ A_log,
    float* __restrict__ sega, float* __restrict__ segh) {
  __shared__ float sx[SEGLEN * 64];
  int s = blockIdx.x, b = blockIdx.y, d = threadIdx.x;
  size_t rbase = ((size_t)b * LL + (size_t)s * SEGLEN) * 64;
#pragma unroll
  for (int j = 0; j < 4; j++)
    *(float4*)(sx + j * 1024 + d * 4) = *(const float4*)(xdbl + rbase + j * 1024 + d * 4);
  __syncthreads();
  if (a_is_integer(A_log, d))
    scan1_body<true>(s, b, d, sx, xc_hi, xc_lo, dtw, dtb, A_log, sega, segh);
  else
    scan1_body<false>(s, b, d, sx, xc_hi, xc_lo, dtw, dtb, A_log, sega, segh);
}

__global__ __launch_bounds__(256) void scan_combine(float* __restrict__ sega,
    const float* __restrict__ segh) {
  int g = blockIdx.x * 256 + threadIdx.x;   // 16384 groups of 4 states
  size_t off = (size_t)(g >> 2) * 16 + (g & 3) * 4;
  float4 h0 = make_float4(0.f, 0.f, 0.f, 0.f);
  for (int s = 0; s < NSEG; s++) {
    size_t q = (size_t)s * 65536 + off;
    float4 a = *(float4*)(sega + q);
    float4 hh = *(float4*)(segh + q);
    *(float4*)(sega + q) = h0;
    h0.x = a.x * h0.x + hh.x;
    h0.y = a.y * h0.y + hh.y;
    h0.z = a.z * h0.z + hh.z;
    h0.w = a.w * h0.w + hh.w;
  }
}

template<bool FAST>
__device__ inline void scan2_body(int s, int b, int d, const float* sx,
    const bf16* __restrict__ xc_hi, const bf16* __restrict__ xc_lo,
    const float* __restrict__ xz, const float* __restrict__ dtw,
    const float* __restrict__ dtb, const float* __restrict__ A_log,
    const float* __restrict__ Dp, const float* __restrict__ sega,
    bf16* __restrict__ y_hi, bf16* __restrict__ y_lo) {
  float wdt[8];
#pragma unroll
  for (int j = 0; j < 8; j++) wdt[j] = dtw[d * 8 + j];
  float bdt = dtb[d];
  float h[DS];
  size_t o = ((size_t)s * 4096 + b * 256 + d) * DS;
#pragma unroll
  for (int n = 0; n < DS; n++) h[n] = sega[o + n];
  float Dd = Dp[d];
  size_t base = (size_t)b * LL + (size_t)s * SEGLEN;
#pragma unroll 4
  for (int t = 0; t < SEGLEN; t++) {
    size_t p = base + t;
    const float* xr = sx + t * 64;
    float dt = bdt;
#pragma unroll
    for (int j = 0; j < 8; j++) dt += xr[j] * wdt[j];
    float dl = softplus_f(dt);
    float u = bf2f(xc_hi[p * 256 + d]) + bf2f(xc_lo[p * 256 + d]);
    float du = dl * u;
    float acc = 0.f;
    if (FAST) {
      float rp[DS];
      make_powers(__expf(-dl), rp);
#pragma unroll
      for (int n = 0; n < DS; n++) {
        h[n] = fmaf(rp[n], h[n], du * xr[8 + n]);
        acc = fmaf(h[n], xr[24 + n], acc);
      }
    } else {
#pragma unroll
      for (int n = 0; n < DS; n++) {
        float dA = __expf(dl * (-__expf(A_log[d * DS + n])));
        h[n] = fmaf(dA, h[n], du * xr[8 + n]);
        acc = fmaf(h[n], xr[24 + n], acc);
      }
    }
    float zv = xz[p * 512 + 256 + d];
    float sig = 1.f / (1.f + __expf(-zv));
    float yv = (acc + u * Dd) * (zv * sig);
    bf16split(yv, y_hi[p * 256 + d], y_lo[p * 256 + d]);
  }
}

__global__ __launch_bounds__(256, 2) void scan_phase2(
    const bf16* __restrict__ xc_hi, const bf16* __restrict__ xc_lo,
    const float* __restrict__ xdbl, const float* __restrict__ xz,
    const float* __restrict__ dtw, const float* __restrict__ dtb,
    const float* __restrict__ A_log, const float* __restrict__ Dp,
    const float* __restrict__ sega, bf16* __restrict__ y_hi,
    bf16* __restrict__ y_lo) {
  __shared__ float sx[SEGLEN * 64];
  int s = blockIdx.x, b = blockIdx.y, d = threadIdx.x;
  size_t rbase = ((size_t)b * LL + (size_t)s * SEGLEN) * 64;
#pragma unroll
  for (int j = 0; j < 4; j++)
    *(float4*)(sx + j * 1024 + d * 4) = *(const float4*)(xdbl + rbase + j * 1024 + d * 4);
  __syncthreads();
  if (a_is_integer(A_log, d))
    scan2_body<true>(s, b, d, sx, xc_hi, xc_lo, xz, dtw, dtb, A_log, Dp, sega, y_hi, y_lo);
  else
    scan2_body<false>(s, b, d, sx, xc_hi, xc_lo, xz, dtw, dtb, A_log, Dp, sega, y_hi, y_lo);
}

// ---------------------------------------------------------------------------
// Final pooling + classifier
// ---------------------------------------------------------------------------
__global__ void zero_kernel(float* __restrict__ p, int n) {
  int i = blockIdx.x * 256 + threadIdx.x;
  if (i < n) p[i] = 0.f;
}

__global__ __launch_bounds__(256) void pool_kernel(const float* __restrict__ xn,
    float* __restrict__ pooled) {
  int b = blockIdx.x, chunk = blockIdx.y;
  int d = threadIdx.x & 127, lh = threadIdx.x >> 7;
  float s = 0.f;
  size_t base = (size_t)b * LL + chunk * 256 + lh * 128;
  for (int i = 0; i < 128; i++) s += xn[(base + i) * DM + d];
  atomicAdd(&pooled[b * DM + d], s * (1.f / LL));
}

__global__ void cls_kernel(const float* __restrict__ pooled,
    const float* __restrict__ cw, const float* __restrict__ cb,
    float* __restrict__ out) {
  int t = threadIdx.x;
  if (t < 80) {
    int b = t / 5, c = t % 5;
    float acc = cb[c];
    for (int d = 0; d < DM; d++) acc += pooled[b * DM + d] * cw[c * DM + d];
    out[t] = acc;
  }
}

// ---------------------------------------------------------------------------
extern "C" void kernel_launch(void* const* d_in, const int* in_sizes, int n_in,
                              void* d_out, int out_size, void* d_ws, size_t ws_size,
                              hipStream_t stream) {
  const float* x         = (const float*)d_in[0];
  const float* enc_w     = (const float*)d_in[1];
  const float* enc_b     = (const float*)d_in[2];
  const float* norm_w    = (const float*)d_in[3];
  const float* in_proj_w = (const float*)d_in[4];
  const float* conv_w    = (const float*)d_in[5];
  const float* conv_b    = (const float*)d_in[6];
  const float* x_proj_w  = (const float*)d_in[7];
  const float* dt_proj_w = (const float*)d_in[8];
  const float* dt_proj_b = (const float*)d_in[9];
  const float* A_log     = (const float*)d_in[10];
  const float* Dp        = (const float*)d_in[11];
  const float* out_proj_w= (const float*)d_in[12];
  const float* norm_f_w  = (const float*)d_in[13];
  const float* cls_w     = (const float*)d_in[14];
  const float* cls_b     = (const float*)d_in[15];
  float* out = (float*)d_out;

  float* ws = (float*)d_ws;
  float* h      = ws;                  // 4,194,304
  float* xz     = ws + 4194304;        // 16,777,216 (reused as fnorm scratch)
  float* xdbl   = ws + 20971520;       // 2,097,152
  float* sega   = ws + 23068672;       // 2,097,152 (NSEG=32)
  float* segh   = ws + 25165824;       // 2,097,152
  float* pooled = ws + 27262976;       // 2048
  bf16* u0     = (bf16*)(ws + 27265024);
  bf16* xn_hi  = u0;                   // 4,194,304
  bf16* xn_lo  = u0 + 4194304;
  bf16* xc_hi  = u0 + 8388608;         // 8,388,608
  bf16* xc_lo  = u0 + 16777216;
  bf16* y_hi   = u0 + 25165824;        // 8,388,608
  bf16* y_lo   = u0 + 33554432;
  bf16* wip_hi = u0 + 41943040;        // 262,144
  bf16* wip_lo = wip_hi + 262144;
  bf16* wxp_hi = wip_lo + 262144;      // 65,536 (padded)
  bf16* wxp_lo = wxp_hi + 65536;
  bf16* wop_hi = wxp_lo + 65536;       // 131,072
  bf16* wop_lo = wop_hi + 131072;
  float* fnorm = xz;                   // xz dead after last scan_phase2

  split_w<<<1024, 256, 0, stream>>>(in_proj_w, wip_hi, wip_lo, 262144);
  split_w_pad<<<256, 256, 0, stream>>>(x_proj_w, wxp_hi, wxp_lo);
  split_w<<<512, 256, 0, stream>>>(out_proj_w, wop_hi, wop_lo, 131072);

  encoder_kernel<<<MP * DM / 256, 256, 0, stream>>>(x, enc_w, enc_b, h);
  rmsnorm_kernel<<<MP / 4, 256, 0, stream>>>(h, norm_w, xn_hi, xn_lo);

  for (int i = 0; i < 4; i++) {
    gemm_mfma<0, 128, 8><<<4096, 256, 0, stream>>>(xn_hi, xn_lo,
        wip_hi + i * 65536, wip_lo + i * 65536, xz, 512);
    conv_silu_kernel<<<MP / 16, 256, 0, stream>>>(xz, conv_w + i * DI * 4,
        conv_b + i * DI, xc_hi, xc_lo);
    gemm_mfma<0, 256, 1><<<512, 256, 0, stream>>>(xc_hi, xc_lo,
        wxp_hi + i * 16384, wxp_lo + i * 16384, xdbl, 64);
    scan_phase1<<<dim3(NSEG, BB), 256, 0, stream>>>(xc_hi, xc_lo, xdbl,
        dt_proj_w + i * 2048, dt_proj_b + i * DI, A_log + i * DI * DS, sega, segh);
    scan_combine<<<64, 256, 0, stream>>>(sega, segh);
    scan_phase2<<<dim3(NSEG, BB), 256, 0, stream>>>(xc_hi, xc_lo, xdbl, xz,
        dt_proj_w + i * 2048, dt_proj_b + i * DI, A_log + i * DI * DS,
        Dp + i * DI, sega, y_hi, y_lo);
    outproj_norm<<<512, 256, 0, stream>>>(y_hi, y_lo,
        wop_hi + i * 32768, wop_lo + i * 32768, h,
        (i < 3) ? norm_w + (i + 1) * DM : norm_f_w,
        (i < 3) ? nullptr : fnorm, xn_hi, xn_lo);
  }

  zero_kernel<<<8, 256, 0, stream>>>(pooled, BB * DM);
  pool_kernel<<<dim3(BB, 8), 256, 0, stream>>>(fnorm, pooled);
  cls_kernel<<<1, 128, 0, stream>>>(pooled, cls_w, cls_b, out);
}